// Round 16
// baseline (184.546 us; speedup 1.0000x reference)
//
#include <hip/hip_runtime.h>
#include <stdint.h>

// Problem constants
#define NB 4
#define TT 2048
#define CC 1024
#define NH 16
#define DD 64
#define BHH (NB*NH)     // 64 (b,h) pairs
#define MROWS (NB*TT)   // 8192

typedef uint16_t u16;
typedef uint32_t u32;
typedef __bf16 bf16x8 __attribute__((ext_vector_type(8)));
typedef float f32x4 __attribute__((ext_vector_type(4)));
typedef float f32x16 __attribute__((ext_vector_type(16)));

__device__ __forceinline__ u16 f2bf(float f) {
    union { float f; uint32_t u; } v; v.f = f;
    uint32_t u = v.u;
    return (u16)((u + 0x7FFF + ((u >> 16) & 1)) >> 16);   // RNE
}

__device__ __forceinline__ u32 cvtpk(float lo, float hi) {
    u32 r;
    asm volatile("v_cvt_pk_bf16_f32 %0, %1, %2" : "=v"(r) : "v"(lo), "v"(hi));
    return r;
}

__device__ __forceinline__ void plswap(u32& a, u32& b) {
    asm volatile("v_permlane32_swap_b32 %0, %1" : "+v"(a), "+v"(b));
}

__device__ __forceinline__ bf16x8 mk8(u32 a, u32 b, u32 c, u32 d) {
    union { u32 u[4]; bf16x8 v; } x;
    x.u[0] = a; x.u[1] = b; x.u[2] = c; x.u[3] = d;
    return x.v;
}

__device__ __forceinline__ void gl_lds16(const u16* g, u16* l) {
    __builtin_amdgcn_global_load_lds(
        (const __attribute__((address_space(1))) unsigned int*)g,
        (__attribute__((address_space(3))) unsigned int*)l, 16, 0, 0);
}

__device__ __forceinline__ f32x4 mfma16(bf16x8 a, bf16x8 b, f32x4 c) {
    return __builtin_amdgcn_mfma_f32_16x16x32_bf16(a, b, c, 0, 0, 0);
}
__device__ __forceinline__ f32x16 mfma32(bf16x8 a, bf16x8 b, f32x16 c) {
    return __builtin_amdgcn_mfma_f32_32x32x16_bf16(a, b, c, 0, 0, 0);
}

#define VM8()  do { asm volatile("s_waitcnt vmcnt(8)" ::: "memory"); \
                    __builtin_amdgcn_sched_barrier(0); } while (0)
#define VM0()  do { asm volatile("s_waitcnt vmcnt(0)" ::: "memory"); \
                    __builtin_amdgcn_sched_barrier(0); } while (0)

// ---------------------------------------------------------------------------
// f32 -> bf16 elementwise convert (vectorized), n % 1024 == 0
// ---------------------------------------------------------------------------
__global__ __launch_bounds__(256) void k_f2b(const float* __restrict__ in,
                                             u16* __restrict__ out, int n) {
    const int i = (blockIdx.x * 256 + threadIdx.x) * 4;
    if (i >= n) return;
    const float4 v = *(const float4*)(in + i);
    ushort4 o;
    o.x = f2bf(v.x); o.y = f2bf(v.y); o.z = f2bf(v.z); o.w = f2bf(v.w);
    *(ushort4*)(out + i) = o;
}

// ---------------------------------------------------------------------------
// Weight transpose + convert: in f32 [R][N] -> out bf16 [N][R]
// ---------------------------------------------------------------------------
__global__ __launch_bounds__(256) void k_transpose_cvt(const float* __restrict__ in,
                                                       u16* __restrict__ out,
                                                       int R, int N) {
    __shared__ float t[32][33];
    const int n0 = blockIdx.x * 32, r0 = blockIdx.y * 32;
    const int c  = threadIdx.x & 31, rq = threadIdx.x >> 5;
#pragma unroll
    for (int i = 0; i < 4; ++i) {
        int r = rq + i * 8;
        t[r][c] = in[(r0 + r) * N + n0 + c];
    }
    __syncthreads();
#pragma unroll
    for (int i = 0; i < 4; ++i) {
        int r = rq + i * 8;
        out[(n0 + r) * R + r0 + c] = f2bf(t[c][r]);
    }
}

// ===========================================================================
// gemm128v5 (round-15, frozen): 128x128, BK=64, dbuf, counted vmcnt, mfma32.
// QKV is at the 2-phase structural floor (~628 TF = m233's measured 607):
// r7/r12/r13/r14/r15 falsified fetch/occupancy/barrier/geometry/inst-count.
// ===========================================================================
__device__ __forceinline__ void gemm128v5(const u16* __restrict__ A,
                                          const u16* __restrict__ Bt,
                                          int m0, int n0, f32x16 acc[2][2]) {
    __shared__ __align__(16) u16 As[2][128 * 64];
    __shared__ __align__(16) u16 Bs[2][128 * 64];
    const int tid = threadIdx.x, l = tid & 63, w = tid >> 6;
    const int wr = w >> 1, wc = w & 1;
    const int lq = l & 31, hi = l >> 5;

    auto stage = [&](int kt, int b) {
#pragma unroll
        for (int line = 0; line < 4; ++line) {
            const int s = line * 4096 + tid * 16;        // linear dest byte
            const int row = s >> 7;                      // 0..127
            const int colb = (s & 127) ^ ((row & 7) << 4);
            const int ldsoff = (line * 4096 + w * 1024) >> 1;
            gl_lds16(A  + (size_t)(m0 + row) * 1024 + kt * 64 + (colb >> 1),
                     &As[b][ldsoff]);
            gl_lds16(Bt + (size_t)(n0 + row) * 1024 + kt * 64 + (colb >> 1),
                     &Bs[b][ldsoff]);
        }
    };

    stage(0, 0);
    stage(1, 1);
    VM8();
    __builtin_amdgcn_s_barrier();

    for (int kt = 0; kt < 16; ++kt) {
        const int b = kt & 1;
#pragma unroll
        for (int ksl = 0; ksl < 4; ++ksl) {
            bf16x8 af[2], bf[2];
#pragma unroll
            for (int mt = 0; mt < 2; ++mt) {
                const int row = wr * 64 + mt * 32 + lq;
                const int byteC = (ksl * 32 + hi * 16) ^ ((row & 7) << 4);
                af[mt] = *(const bf16x8*)&As[b][(row * 128 + byteC) >> 1];
            }
#pragma unroll
            for (int nt = 0; nt < 2; ++nt) {
                const int row = wc * 64 + nt * 32 + lq;
                const int byteC = (ksl * 32 + hi * 16) ^ ((row & 7) << 4);
                bf[nt] = *(const bf16x8*)&Bs[b][(row * 128 + byteC) >> 1];
            }
            acc[0][0] = mfma32(af[0], bf[0], acc[0][0]);
            acc[0][1] = mfma32(af[0], bf[1], acc[0][1]);
            acc[1][0] = mfma32(af[1], bf[0], acc[1][0]);
            acc[1][1] = mfma32(af[1], bf[1], acc[1][1]);
        }

        if (kt == 15) break;

        __builtin_amdgcn_s_barrier();
        if (kt + 2 < 16) {
            stage(kt + 2, b);
            VM8();
        } else {
            VM0();
        }
        __builtin_amdgcn_s_barrier();
    }
}

// ---------------------------------------------------------------------------
// QKV GEMM (gemm128v5) + XCD-chunked swizzle + bias, scatter Q/K/Vt
// Q pre-scaled by 0.125*log2(e) (v6-proven): attn gets log2-domain scores.
// ---------------------------------------------------------------------------
__global__ __launch_bounds__(256, 2) void k_gemm_qkv(const u16* __restrict__ X,
                                                     const u16* __restrict__ Wt,
                                                     const float* __restrict__ bias,
                                                     u16* __restrict__ Qo,
                                                     u16* __restrict__ Ko,
                                                     u16* __restrict__ Vto) {
    const int id = blockIdx.x;
    const int xcd = id & 7, lid = id >> 3;     // lid 0..191
    const int lm = lid & 7, ln = lid >> 3;     // 8 m x 24 n per XCD
    const int m0 = (xcd * 8 + lm) * 128;
    const int n0 = ln * 128;

    f32x16 acc[2][2] = {};
    gemm128v5(X, Wt, m0, n0, acc);

    const float C2 = 0.18033688011112042f;     // 0.125 * log2(e)
    const int tid = threadIdx.x, l = tid & 63, w = tid >> 6;
    const int wr = w >> 1, wc = w & 1, lq = l & 31, hi = l >> 5;
#pragma unroll
    for (int nt = 0; nt < 2; ++nt) {
        const int c = n0 + wc * 64 + nt * 32 + lq;
        const float bv = bias[c];
        const int which = c >> 10, cc = c & 1023, h = cc >> 6, d = cc & 63;
#pragma unroll
        for (int mt = 0; mt < 2; ++mt) {
#pragma unroll
            for (int r = 0; r < 16; ++r) {
                const int rowl = (r & 3) + 8 * (r >> 2) + 4 * hi;
                const int row = m0 + wr * 64 + mt * 32 + rowl;
                const int b = row >> 11, t = row & 2047;
                const int bh = b * NH + h;
                const float v = acc[mt][nt][r] + bv;
                if (which == 0)      Qo[(bh * TT + t) * DD + d] = f2bf(v * C2);
                else if (which == 1) Ko[(bh * TT + t) * DD + d] = f2bf(v);
                else                 Vto[(bh * DD + d) * TT + t] = f2bf(v);
            }
        }
    }
}

// ---------------------------------------------------------------------------
// Proj GEMM (gemm128v5) + XCD swizzle + bias -> out f32 [8192][1024]
// ---------------------------------------------------------------------------
__global__ __launch_bounds__(256, 2) void k_gemm_proj(const u16* __restrict__ Yin,
                                                      const u16* __restrict__ Wt,
                                                      const float* __restrict__ bias,
                                                      float* __restrict__ out) {
    const int id = blockIdx.x;
    const int xcd = id & 7, lid = id >> 3;     // lid 0..63
    const int lm = lid & 7, ln = lid >> 3;     // 8 m x 8 n per XCD
    const int m0 = (xcd * 8 + lm) * 128;
    const int n0 = ln * 128;

    f32x16 acc[2][2] = {};
    gemm128v5(Yin, Wt, m0, n0, acc);

    const int tid = threadIdx.x, l = tid & 63, w = tid >> 6;
    const int wr = w >> 1, wc = w & 1, lq = l & 31, hi = l >> 5;
#pragma unroll
    for (int nt = 0; nt < 2; ++nt) {
        const int c = n0 + wc * 64 + nt * 32 + lq;
        const float bv = bias[c];
#pragma unroll
        for (int mt = 0; mt < 2; ++mt) {
#pragma unroll
            for (int r = 0; r < 16; ++r) {
                const int rowl = (r & 3) + 8 * (r >> 2) + 4 * hi;
                const int row = m0 + wr * 64 + mt * 32 + rowl;
                out[row * CC + c] = acc[mt][nt][r] + bv;
            }
        }
    }
}

// ---------------------------------------------------------------------------
// Causal flash attention v8 — v7 softmax/PV with KVBLK=128 tiles:
//  - per kv-tile: 128 kv staged as K[128][128B] + V in TWO [64][128B]
//    kv-half sub-tiles (keeps the measured-0-conflict 128B-row swizzle)
//  - barrier count halves (qi+1 vs 2qi+2); prefetch window doubles
//  - 4 substeps of 32 kv per tile; softmax identical to v7 (log2 domain,
//    T13 threshold rescale)
//  - LDS 64 KiB -> 2 blocks/CU
// ---------------------------------------------------------------------------
__global__ __launch_bounds__(256) void k_attn(const u16* __restrict__ Qg_,
                                              const u16* __restrict__ Kg_,
                                              const u16* __restrict__ Vg_,
                                              u16* __restrict__ Y) {
    __shared__ __align__(16) u16 Ks[2][128 * 64];
    __shared__ __align__(16) u16 Vs[2][128 * 64];   // 2 sub-tiles of [64][128B]

    const int id = blockIdx.x;
    const int qi = 15 - (id >> 6);         // work-descending
    const int bh = id & 63;
    const int q0 = qi * 128;
    const u16* Qg = Qg_ + (size_t)bh * TT * DD;
    const u16* Kg = Kg_ + (size_t)bh * TT * DD;
    const u16* Vg = Vg_ + (size_t)bh * DD * TT;
    const int tid = threadIdx.x, l = tid & 63, w = tid >> 6;
    const int lq = l & 31, hi = l >> 5;
    const int qs = q0 + w * 32;

    unsigned dmask = 0;
#pragma unroll
    for (int r = 0; r < 16; ++r) {
        const int kvloc = (r & 3) + 8 * (r >> 2) + 4 * hi;
        if (kvloc > lq) dmask |= (1u << r);
    }

    const u16* qrow = Qg + (qs + lq) * DD + hi * 8;
    bf16x8 qf0 = *(const bf16x8*)(qrow);
    bf16x8 qf1 = *(const bf16x8*)(qrow + 16);
    bf16x8 qf2 = *(const bf16x8*)(qrow + 32);
    bf16x8 qf3 = *(const bf16x8*)(qrow + 48);

    f32x16 o0 = {}, o1 = {};
    float mrun = -1e30f, lrun = 0.f;
    const int nt = qi + 1;                 // 128-kv tiles

    // stage K [128][128B] (4 calls) + V two [64][128B] sub-tiles (4 calls)
    auto stage = [&](int t, int b) {
        const int kv0 = t * 128;
#pragma unroll
        for (int iss = 0; iss < 4; ++iss) {            // K: 16KB
            const int s = iss * 4096 + tid * 16;
            const int row = s >> 7;                    // 0..127
            const int colb = (s & 127) ^ ((row & 7) << 4);
            gl_lds16(Kg + (kv0 + row) * DD + (colb >> 1),
                     &Ks[b][(iss * 4096 + w * 1024) >> 1]);
        }
#pragma unroll
        for (int v = 0; v < 2; ++v)                    // V: 2 x 8KB
#pragma unroll
            for (int iss = 0; iss < 2; ++iss) {
                const int s = iss * 4096 + tid * 16;
                const int row = s >> 7;                // 0..63
                const int colb = (s & 127) ^ ((row & 7) << 4);
                gl_lds16(Vg + row * TT + kv0 + v * 64 + (colb >> 1),
                         &Vs[b][(v * 8192 + iss * 4096 + w * 1024) >> 1]);
            }
    };

    stage(0, 0);
    __syncthreads();

    for (int t = 0; t < nt; ++t) {
        const int b = t & 1;
        if (t + 1 < nt) stage(t + 1, b ^ 1);
        const int kv0 = t * 128;

#pragma unroll
        for (int s = 0; s < 4; ++s) {
            const int kvs = kv0 + 32 * s;
            if (kvs > qs) continue;

            // ---- S^T (log2 domain) = K Q' from LDS ----
            f32x16 st = {};
#pragma unroll
            for (int i = 0; i < 4; ++i) {
                const int row = 32 * s + lq;           // 0..127
                const int byte = (32 * i + 16 * hi) ^ ((row & 7) << 4);
                const bf16x8 kf = *(const bf16x8*)&Ks[b][(row * 128 + byte) >> 1];
                if (i == 0) st = mfma32(kf, qf0, st);
                else if (i == 1) st = mfma32(kf, qf1, st);
                else if (i == 2) st = mfma32(kf, qf2, st);
                else st = mfma32(kf, qf3, st);
            }

            if (kvs == qs) {                   // diagonal: causal mask
#pragma unroll
                for (int r = 0; r < 16; ++r)
                    if ((dmask >> r) & 1) st[r] = -1e30f;
            }

            // ---- column max (in-lane + partner exchange) ----
            float mx = st[0];
#pragma unroll
            for (int r = 1; r < 16; ++r) mx = fmaxf(mx, st[r]);
            mx = fmaxf(mx, __shfl_xor(mx, 32));

            // T13: rescale only when growth exceeds 8 (P then <= 2^8)
            if (!__all(mx - mrun <= 8.0f)) {
                const float mn = fmaxf(mrun, mx);
                const float scl = __builtin_amdgcn_exp2f(mrun - mn);
                mrun = mn;
                lrun *= scl;
#pragma unroll
                for (int r = 0; r < 16; ++r) { o0[r] *= scl; o1[r] *= scl; }
            }

            // ---- P = exp2(st - m); psum; pack to bf16 pairs ----
            float psum = 0.f;
            u32 pk0, pk1, pk2, pk3, pk4, pk5, pk6, pk7;
            {
                float pa, pb;
                pa = __builtin_amdgcn_exp2f(st[0] - mrun);
                pb = __builtin_amdgcn_exp2f(st[1] - mrun);
                psum += pa + pb; pk0 = cvtpk(pa, pb);
                pa = __builtin_amdgcn_exp2f(st[2] - mrun);
                pb = __builtin_amdgcn_exp2f(st[3] - mrun);
                psum += pa + pb; pk1 = cvtpk(pa, pb);
                pa = __builtin_amdgcn_exp2f(st[4] - mrun);
                pb = __builtin_amdgcn_exp2f(st[5] - mrun);
                psum += pa + pb; pk2 = cvtpk(pa, pb);
                pa = __builtin_amdgcn_exp2f(st[6] - mrun);
                pb = __builtin_amdgcn_exp2f(st[7] - mrun);
                psum += pa + pb; pk3 = cvtpk(pa, pb);
                pa = __builtin_amdgcn_exp2f(st[8] - mrun);
                pb = __builtin_amdgcn_exp2f(st[9] - mrun);
                psum += pa + pb; pk4 = cvtpk(pa, pb);
                pa = __builtin_amdgcn_exp2f(st[10] - mrun);
                pb = __builtin_amdgcn_exp2f(st[11] - mrun);
                psum += pa + pb; pk5 = cvtpk(pa, pb);
                pa = __builtin_amdgcn_exp2f(st[12] - mrun);
                pb = __builtin_amdgcn_exp2f(st[13] - mrun);
                psum += pa + pb; pk6 = cvtpk(pa, pb);
                pa = __builtin_amdgcn_exp2f(st[14] - mrun);
                pb = __builtin_amdgcn_exp2f(st[15] - mrun);
                psum += pa + pb; pk7 = cvtpk(pa, pb);
            }
            lrun += psum;

            plswap(pk0, pk2); plswap(pk1, pk3);
            plswap(pk4, pk6); plswap(pk5, pk7);
            const bf16x8 pf0 = mk8(pk0, pk1, pk2, pk3);   // kv +0..15
            const bf16x8 pf1 = mk8(pk4, pk5, pk6, pk7);   // kv +16..31

            // ---- O^T += V^T P from LDS (sub-tile s>>1, half s&1) ----
            const int sv = s >> 1, sh = s & 1;
#pragma unroll
            for (int dh = 0; dh < 2; ++dh) {
#pragma unroll
                for (int ks = 0; ks < 2; ++ks) {
                    const int row = 32 * dh + lq;
                    const int byte = (64 * sh + 32 * ks + 16 * hi) ^ ((row & 7) << 4);
                    const bf16x8 vf =
                        *(const bf16x8*)&Vs[b][(sv * 8192 + row * 128 + byte) >> 1];
                    if (dh == 0) o0 = mfma32(vf, ks ? pf1 : pf0, o0);
                    else         o1 = mfma32(vf, ks ? pf1 : pf0, o1);
                }
            }
        }
        if (t + 1 < nt) __syncthreads();
    }

    lrun += __shfl_xor(lrun, 32);
    const float inv = 1.0f / lrun;
    const int bb = bh >> 4, h = bh & 15;
    u16* yrow = Y + (size_t)(bb * TT + qs + lq) * CC + h * DD;
#pragma unroll
    for (int rq = 0; rq < 4; ++rq) {
        const int d0 = 8 * rq + 4 * hi;
        const u32 w0 = cvtpk(o0[rq * 4 + 0] * inv, o0[rq * 4 + 1] * inv);
        const u32 w1 = cvtpk(o0[rq * 4 + 2] * inv, o0[rq * 4 + 3] * inv);
        *(uint2*)&yrow[d0] = make_uint2(w0, w1);
        const u32 w2 = cvtpk(o1[rq * 4 + 0] * inv, o1[rq * 4 + 1] * inv);
        const u32 w3 = cvtpk(o1[rq * 4 + 2] * inv, o1[rq * 4 + 3] * inv);
        *(uint2*)&yrow[32 + d0] = make_uint2(w2, w3);
    }
}

// ---------------------------------------------------------------------------
extern "C" void kernel_launch(void* const* d_in, const int* in_sizes, int n_in,
                              void* d_out, int out_size, void* d_ws, size_t ws_size,
                              hipStream_t stream) {
    const float* X  = (const float*)d_in[0];   // [4,2048,1024] f32
    const float* Wa = (const float*)d_in[1];   // [1024,3072]  f32
    const float* ba = (const float*)d_in[2];   // [3072]       f32
    const float* Wp = (const float*)d_in[3];   // [1024,1024]  f32
    const float* bp = (const float*)d_in[4];   // [1024]       f32
    float* out = (float*)d_out;                // [8192,1024]  f32

    u16* ws  = (u16*)d_ws;
    u16* Xb  = ws;                                    // 8192*1024
    u16* WtA = Xb + (size_t)MROWS * CC;               // 3072*1024
    u16* WtP = WtA + 3072 * 1024;                     // 1024*1024
    u16* Qb  = WtP + 1024 * 1024;                     // 64*2048*64
    u16* Kb  = Qb + (size_t)BHH * TT * DD;
    u16* Vtb = Kb + (size_t)BHH * TT * DD;
    u16* Yb  = Vtb + (size_t)BHH * TT * DD;           // 8192*1024

    k_f2b<<<dim3(MROWS * CC / 1024), 256, 0, stream>>>(X, Xb, MROWS * CC);
    k_transpose_cvt<<<dim3(96, 32), 256, 0, stream>>>(Wa, WtA, 1024, 3072);
    k_transpose_cvt<<<dim3(32, 32), 256, 0, stream>>>(Wp, WtP, 1024, 1024);
    k_gemm_qkv<<<dim3(1536), 256, 0, stream>>>(Xb, WtA, ba, Qb, Kb, Vtb);
    k_attn<<<dim3(1024), 256, 0, stream>>>(Qb, Kb, Vtb, Yb);
    k_gemm_proj<<<dim3(512), 256, 0, stream>>>(Yb, WtP, bp, out);
}

// Round 17
// 177.536 us; speedup vs baseline: 1.0395x; 1.0395x over previous
//
#include <hip/hip_runtime.h>
#include <stdint.h>

// Problem constants
#define NB 4
#define TT 2048
#define CC 1024
#define NH 16
#define DD 64
#define BHH (NB*NH)     // 64 (b,h) pairs
#define MROWS (NB*TT)   // 8192

typedef uint16_t u16;
typedef uint32_t u32;
typedef __bf16 bf16x8 __attribute__((ext_vector_type(8)));
typedef float f32x4 __attribute__((ext_vector_type(4)));
typedef float f32x16 __attribute__((ext_vector_type(16)));

__device__ __forceinline__ u16 f2bf(float f) {
    union { float f; uint32_t u; } v; v.f = f;
    uint32_t u = v.u;
    return (u16)((u + 0x7FFF + ((u >> 16) & 1)) >> 16);   // RNE
}

__device__ __forceinline__ u32 cvtpk(float lo, float hi) {
    u32 r;
    asm volatile("v_cvt_pk_bf16_f32 %0, %1, %2" : "=v"(r) : "v"(lo), "v"(hi));
    return r;
}

__device__ __forceinline__ void plswap(u32& a, u32& b) {
    asm volatile("v_permlane32_swap_b32 %0, %1" : "+v"(a), "+v"(b));
}

__device__ __forceinline__ bf16x8 mk8(u32 a, u32 b, u32 c, u32 d) {
    union { u32 u[4]; bf16x8 v; } x;
    x.u[0] = a; x.u[1] = b; x.u[2] = c; x.u[3] = d;
    return x.v;
}

__device__ __forceinline__ void gl_lds16(const u16* g, u16* l) {
    __builtin_amdgcn_global_load_lds(
        (const __attribute__((address_space(1))) unsigned int*)g,
        (__attribute__((address_space(3))) unsigned int*)l, 16, 0, 0);
}

__device__ __forceinline__ f32x4 mfma16(bf16x8 a, bf16x8 b, f32x4 c) {
    return __builtin_amdgcn_mfma_f32_16x16x32_bf16(a, b, c, 0, 0, 0);
}
__device__ __forceinline__ f32x16 mfma32(bf16x8 a, bf16x8 b, f32x16 c) {
    return __builtin_amdgcn_mfma_f32_32x32x16_bf16(a, b, c, 0, 0, 0);
}

#define VM8()  do { asm volatile("s_waitcnt vmcnt(8)" ::: "memory"); \
                    __builtin_amdgcn_sched_barrier(0); } while (0)
#define VM0()  do { asm volatile("s_waitcnt vmcnt(0)" ::: "memory"); \
                    __builtin_amdgcn_sched_barrier(0); } while (0)
#define SETP(x) __builtin_amdgcn_s_setprio(x)

// ---------------------------------------------------------------------------
// f32 -> bf16 elementwise convert (vectorized), n % 1024 == 0
// ---------------------------------------------------------------------------
__global__ __launch_bounds__(256) void k_f2b(const float* __restrict__ in,
                                             u16* __restrict__ out, int n) {
    const int i = (blockIdx.x * 256 + threadIdx.x) * 4;
    if (i >= n) return;
    const float4 v = *(const float4*)(in + i);
    ushort4 o;
    o.x = f2bf(v.x); o.y = f2bf(v.y); o.z = f2bf(v.z); o.w = f2bf(v.w);
    *(ushort4*)(out + i) = o;
}

// ---------------------------------------------------------------------------
// Weight transpose + convert: in f32 [R][N] -> out bf16 [N][R]
// ---------------------------------------------------------------------------
__global__ __launch_bounds__(256) void k_transpose_cvt(const float* __restrict__ in,
                                                       u16* __restrict__ out,
                                                       int R, int N) {
    __shared__ float t[32][33];
    const int n0 = blockIdx.x * 32, r0 = blockIdx.y * 32;
    const int c  = threadIdx.x & 31, rq = threadIdx.x >> 5;
#pragma unroll
    for (int i = 0; i < 4; ++i) {
        int r = rq + i * 8;
        t[r][c] = in[(r0 + r) * N + n0 + c];
    }
    __syncthreads();
#pragma unroll
    for (int i = 0; i < 4; ++i) {
        int r = rq + i * 8;
        out[(n0 + r) * R + r0 + c] = f2bf(t[c][r]);
    }
}

// ===========================================================================
// gemm128v5 (round-15, frozen): 128x128, BK=64, dbuf, counted vmcnt, mfma32.
// QKV is at the 2-phase structural floor (~628 TF = m233's measured 607):
// r7/r12/r13/r14/r15 falsified fetch/occupancy/barrier/geometry/inst-count.
// ===========================================================================
__device__ __forceinline__ void gemm128v5(const u16* __restrict__ A,
                                          const u16* __restrict__ Bt,
                                          int m0, int n0, f32x16 acc[2][2]) {
    __shared__ __align__(16) u16 As[2][128 * 64];
    __shared__ __align__(16) u16 Bs[2][128 * 64];
    const int tid = threadIdx.x, l = tid & 63, w = tid >> 6;
    const int wr = w >> 1, wc = w & 1;
    const int lq = l & 31, hi = l >> 5;

    auto stage = [&](int kt, int b) {
#pragma unroll
        for (int line = 0; line < 4; ++line) {
            const int s = line * 4096 + tid * 16;        // linear dest byte
            const int row = s >> 7;                      // 0..127
            const int colb = (s & 127) ^ ((row & 7) << 4);
            const int ldsoff = (line * 4096 + w * 1024) >> 1;
            gl_lds16(A  + (size_t)(m0 + row) * 1024 + kt * 64 + (colb >> 1),
                     &As[b][ldsoff]);
            gl_lds16(Bt + (size_t)(n0 + row) * 1024 + kt * 64 + (colb >> 1),
                     &Bs[b][ldsoff]);
        }
    };

    stage(0, 0);
    stage(1, 1);
    VM8();
    __builtin_amdgcn_s_barrier();

    for (int kt = 0; kt < 16; ++kt) {
        const int b = kt & 1;
#pragma unroll
        for (int ksl = 0; ksl < 4; ++ksl) {
            bf16x8 af[2], bf[2];
#pragma unroll
            for (int mt = 0; mt < 2; ++mt) {
                const int row = wr * 64 + mt * 32 + lq;
                const int byteC = (ksl * 32 + hi * 16) ^ ((row & 7) << 4);
                af[mt] = *(const bf16x8*)&As[b][(row * 128 + byteC) >> 1];
            }
#pragma unroll
            for (int nt = 0; nt < 2; ++nt) {
                const int row = wc * 64 + nt * 32 + lq;
                const int byteC = (ksl * 32 + hi * 16) ^ ((row & 7) << 4);
                bf[nt] = *(const bf16x8*)&Bs[b][(row * 128 + byteC) >> 1];
            }
            acc[0][0] = mfma32(af[0], bf[0], acc[0][0]);
            acc[0][1] = mfma32(af[0], bf[1], acc[0][1]);
            acc[1][0] = mfma32(af[1], bf[0], acc[1][0]);
            acc[1][1] = mfma32(af[1], bf[1], acc[1][1]);
        }

        if (kt == 15) break;

        __builtin_amdgcn_s_barrier();
        if (kt + 2 < 16) {
            stage(kt + 2, b);
            VM8();
        } else {
            VM0();
        }
        __builtin_amdgcn_s_barrier();
    }
}

// ---------------------------------------------------------------------------
// QKV GEMM (gemm128v5) + XCD-chunked swizzle + bias, scatter Q/K/Vt
// Q pre-scaled by 0.125*log2(e) (v6-proven): attn gets log2-domain scores.
// ---------------------------------------------------------------------------
__global__ __launch_bounds__(256, 2) void k_gemm_qkv(const u16* __restrict__ X,
                                                     const u16* __restrict__ Wt,
                                                     const float* __restrict__ bias,
                                                     u16* __restrict__ Qo,
                                                     u16* __restrict__ Ko,
                                                     u16* __restrict__ Vto) {
    const int id = blockIdx.x;
    const int xcd = id & 7, lid = id >> 3;     // lid 0..191
    const int lm = lid & 7, ln = lid >> 3;     // 8 m x 24 n per XCD
    const int m0 = (xcd * 8 + lm) * 128;
    const int n0 = ln * 128;

    f32x16 acc[2][2] = {};
    gemm128v5(X, Wt, m0, n0, acc);

    const float C2 = 0.18033688011112042f;     // 0.125 * log2(e)
    const int tid = threadIdx.x, l = tid & 63, w = tid >> 6;
    const int wr = w >> 1, wc = w & 1, lq = l & 31, hi = l >> 5;
#pragma unroll
    for (int nt = 0; nt < 2; ++nt) {
        const int c = n0 + wc * 64 + nt * 32 + lq;
        const float bv = bias[c];
        const int which = c >> 10, cc = c & 1023, h = cc >> 6, d = cc & 63;
#pragma unroll
        for (int mt = 0; mt < 2; ++mt) {
#pragma unroll
            for (int r = 0; r < 16; ++r) {
                const int rowl = (r & 3) + 8 * (r >> 2) + 4 * hi;
                const int row = m0 + wr * 64 + mt * 32 + rowl;
                const int b = row >> 11, t = row & 2047;
                const int bh = b * NH + h;
                const float v = acc[mt][nt][r] + bv;
                if (which == 0)      Qo[(bh * TT + t) * DD + d] = f2bf(v * C2);
                else if (which == 1) Ko[(bh * TT + t) * DD + d] = f2bf(v);
                else                 Vto[(bh * DD + d) * TT + t] = f2bf(v);
            }
        }
    }
}

// ---------------------------------------------------------------------------
// Proj GEMM (gemm128v5) + XCD swizzle + bias -> out f32 [8192][1024]
// ---------------------------------------------------------------------------
__global__ __launch_bounds__(256, 2) void k_gemm_proj(const u16* __restrict__ Yin,
                                                      const u16* __restrict__ Wt,
                                                      const float* __restrict__ bias,
                                                      float* __restrict__ out) {
    const int id = blockIdx.x;
    const int xcd = id & 7, lid = id >> 3;     // lid 0..63
    const int lm = lid & 7, ln = lid >> 3;     // 8 m x 8 n per XCD
    const int m0 = (xcd * 8 + lm) * 128;
    const int n0 = ln * 128;

    f32x16 acc[2][2] = {};
    gemm128v5(Yin, Wt, m0, n0, acc);

    const int tid = threadIdx.x, l = tid & 63, w = tid >> 6;
    const int wr = w >> 1, wc = w & 1, lq = l & 31, hi = l >> 5;
#pragma unroll
    for (int nt = 0; nt < 2; ++nt) {
        const int c = n0 + wc * 64 + nt * 32 + lq;
        const float bv = bias[c];
#pragma unroll
        for (int mt = 0; mt < 2; ++mt) {
#pragma unroll
            for (int r = 0; r < 16; ++r) {
                const int rowl = (r & 3) + 8 * (r >> 2) + 4 * hi;
                const int row = m0 + wr * 64 + mt * 32 + rowl;
                out[row * CC + c] = acc[mt][nt][r] + bv;
            }
        }
    }
}

// ---------------------------------------------------------------------------
// Causal flash attention v9 — round-11 v7 (KVBLK=64, proven fastest) +
// T5 s_setprio(1) around QK^T and PV MFMA clusters (m191: +4-7% on attn,
// independent-block regime; applied to attn ONLY — null on lockstep GEMM).
// ---------------------------------------------------------------------------
__global__ __launch_bounds__(256) void k_attn(const u16* __restrict__ Qg_,
                                              const u16* __restrict__ Kg_,
                                              const u16* __restrict__ Vg_,
                                              u16* __restrict__ Y) {
    __shared__ __align__(16) u16 Ks[2][64 * 64];
    __shared__ __align__(16) u16 Vs[2][64 * 64];

    const int id = blockIdx.x;
    const int qi = 15 - (id >> 6);         // work-descending
    const int bh = id & 63;
    const int q0 = qi * 128;
    const u16* Qg = Qg_ + (size_t)bh * TT * DD;
    const u16* Kg = Kg_ + (size_t)bh * TT * DD;
    const u16* Vg = Vg_ + (size_t)bh * DD * TT;
    const int tid = threadIdx.x, l = tid & 63, w = tid >> 6;
    const int lq = l & 31, hi = l >> 5;
    const int qs = q0 + w * 32;

    unsigned dmask = 0;
#pragma unroll
    for (int r = 0; r < 16; ++r) {
        const int kvloc = (r & 3) + 8 * (r >> 2) + 4 * hi;
        if (kvloc > lq) dmask |= (1u << r);
    }

    const u16* qrow = Qg + (qs + lq) * DD + hi * 8;
    bf16x8 qf0 = *(const bf16x8*)(qrow);
    bf16x8 qf1 = *(const bf16x8*)(qrow + 16);
    bf16x8 qf2 = *(const bf16x8*)(qrow + 32);
    bf16x8 qf3 = *(const bf16x8*)(qrow + 48);

    f32x16 o0 = {}, o1 = {};
    float mrun = -1e30f, lrun = 0.f;
    const int nt = 2 * qi + 2;

    auto stage = [&](int t, int b) {
        const int kv0 = t * 64;
#pragma unroll
        for (int iss = 0; iss < 2; ++iss) {
            const int s = iss * 4096 + tid * 16;
            const int row = s >> 7;
            const int colb = (s & 127) ^ ((row & 7) << 4);
            const int ldsoff = (iss * 4096 + w * 1024) >> 1;
            gl_lds16(Kg + (kv0 + row) * DD + (colb >> 1), &Ks[b][ldsoff]);
            gl_lds16(Vg + row * TT + kv0 + (colb >> 1),   &Vs[b][ldsoff]);
        }
    };

    stage(0, 0);
    __syncthreads();

    for (int t = 0; t < nt; ++t) {
        const int b = t & 1;
        if (t + 1 < nt) stage(t + 1, b ^ 1);
        const int kv0 = t * 64;

#pragma unroll
        for (int s = 0; s < 2; ++s) {
            const int kvs = kv0 + 32 * s;
            if (kvs > qs) continue;

            // ---- S^T (log2 domain) = K Q' from LDS ----
            f32x16 st = {};
            SETP(1);
#pragma unroll
            for (int i = 0; i < 4; ++i) {
                const int row = 32 * s + lq;
                const int byte = (32 * i + 16 * hi) ^ ((row & 7) << 4);
                const bf16x8 kf = *(const bf16x8*)&Ks[b][(row * 128 + byte) >> 1];
                if (i == 0) st = mfma32(kf, qf0, st);
                else if (i == 1) st = mfma32(kf, qf1, st);
                else if (i == 2) st = mfma32(kf, qf2, st);
                else st = mfma32(kf, qf3, st);
            }
            SETP(0);

            if (kvs == qs) {                   // diagonal: causal mask
#pragma unroll
                for (int r = 0; r < 16; ++r)
                    if ((dmask >> r) & 1) st[r] = -1e30f;
            }

            // ---- column max (in-lane + partner exchange) ----
            float mx = st[0];
#pragma unroll
            for (int r = 1; r < 16; ++r) mx = fmaxf(mx, st[r]);
            mx = fmaxf(mx, __shfl_xor(mx, 32));

            // T13: rescale only when growth exceeds 8 (P then <= 2^8)
            if (!__all(mx - mrun <= 8.0f)) {
                const float mn = fmaxf(mrun, mx);
                const float scl = __builtin_amdgcn_exp2f(mrun - mn);
                mrun = mn;
                lrun *= scl;
#pragma unroll
                for (int r = 0; r < 16; ++r) { o0[r] *= scl; o1[r] *= scl; }
            }

            // ---- P = exp2(st - m); psum; pack to bf16 pairs ----
            float psum = 0.f;
            u32 pk0, pk1, pk2, pk3, pk4, pk5, pk6, pk7;
            {
                float pa, pb;
                pa = __builtin_amdgcn_exp2f(st[0] - mrun);
                pb = __builtin_amdgcn_exp2f(st[1] - mrun);
                psum += pa + pb; pk0 = cvtpk(pa, pb);
                pa = __builtin_amdgcn_exp2f(st[2] - mrun);
                pb = __builtin_amdgcn_exp2f(st[3] - mrun);
                psum += pa + pb; pk1 = cvtpk(pa, pb);
                pa = __builtin_amdgcn_exp2f(st[4] - mrun);
                pb = __builtin_amdgcn_exp2f(st[5] - mrun);
                psum += pa + pb; pk2 = cvtpk(pa, pb);
                pa = __builtin_amdgcn_exp2f(st[6] - mrun);
                pb = __builtin_amdgcn_exp2f(st[7] - mrun);
                psum += pa + pb; pk3 = cvtpk(pa, pb);
                pa = __builtin_amdgcn_exp2f(st[8] - mrun);
                pb = __builtin_amdgcn_exp2f(st[9] - mrun);
                psum += pa + pb; pk4 = cvtpk(pa, pb);
                pa = __builtin_amdgcn_exp2f(st[10] - mrun);
                pb = __builtin_amdgcn_exp2f(st[11] - mrun);
                psum += pa + pb; pk5 = cvtpk(pa, pb);
                pa = __builtin_amdgcn_exp2f(st[12] - mrun);
                pb = __builtin_amdgcn_exp2f(st[13] - mrun);
                psum += pa + pb; pk6 = cvtpk(pa, pb);
                pa = __builtin_amdgcn_exp2f(st[14] - mrun);
                pb = __builtin_amdgcn_exp2f(st[15] - mrun);
                psum += pa + pb; pk7 = cvtpk(pa, pb);
            }
            lrun += psum;

            plswap(pk0, pk2); plswap(pk1, pk3);
            plswap(pk4, pk6); plswap(pk5, pk7);
            const bf16x8 pf0 = mk8(pk0, pk1, pk2, pk3);   // kv +0..15
            const bf16x8 pf1 = mk8(pk4, pk5, pk6, pk7);   // kv +16..31

            // ---- O^T += V^T P from LDS (A = V^T: row=d, k=kv) ----
            SETP(1);
#pragma unroll
            for (int dh = 0; dh < 2; ++dh) {
#pragma unroll
                for (int ks = 0; ks < 2; ++ks) {
                    const int row = 32 * dh + lq;
                    const int byte = (64 * s + 32 * ks + 16 * hi) ^ ((row & 7) << 4);
                    const bf16x8 vf = *(const bf16x8*)&Vs[b][(row * 128 + byte) >> 1];
                    if (dh == 0) o0 = mfma32(vf, ks ? pf1 : pf0, o0);
                    else         o1 = mfma32(vf, ks ? pf1 : pf0, o1);
                }
            }
            SETP(0);
        }
        if (t + 1 < nt) __syncthreads();
    }

    lrun += __shfl_xor(lrun, 32);
    const float inv = 1.0f / lrun;
    const int bb = bh >> 4, h = bh & 15;
    u16* yrow = Y + (size_t)(bb * TT + qs + lq) * CC + h * DD;
#pragma unroll
    for (int rq = 0; rq < 4; ++rq) {
        const int d0 = 8 * rq + 4 * hi;
        const u32 w0 = cvtpk(o0[rq * 4 + 0] * inv, o0[rq * 4 + 1] * inv);
        const u32 w1 = cvtpk(o0[rq * 4 + 2] * inv, o0[rq * 4 + 3] * inv);
        *(uint2*)&yrow[d0] = make_uint2(w0, w1);
        const u32 w2 = cvtpk(o1[rq * 4 + 0] * inv, o1[rq * 4 + 1] * inv);
        const u32 w3 = cvtpk(o1[rq * 4 + 2] * inv, o1[rq * 4 + 3] * inv);
        *(uint2*)&yrow[32 + d0] = make_uint2(w2, w3);
    }
}

// ---------------------------------------------------------------------------
extern "C" void kernel_launch(void* const* d_in, const int* in_sizes, int n_in,
                              void* d_out, int out_size, void* d_ws, size_t ws_size,
                              hipStream_t stream) {
    const float* X  = (const float*)d_in[0];   // [4,2048,1024] f32
    const float* Wa = (const float*)d_in[1];   // [1024,3072]  f32
    const float* ba = (const float*)d_in[2];   // [3072]       f32
    const float* Wp = (const float*)d_in[3];   // [1024,1024]  f32
    const float* bp = (const float*)d_in[4];   // [1024]       f32
    float* out = (float*)d_out;                // [8192,1024]  f32

    u16* ws  = (u16*)d_ws;
    u16* Xb  = ws;                                    // 8192*1024
    u16* WtA = Xb + (size_t)MROWS * CC;               // 3072*1024
    u16* WtP = WtA + 3072 * 1024;                     // 1024*1024
    u16* Qb  = WtP + 1024 * 1024;                     // 64*2048*64
    u16* Kb  = Qb + (size_t)BHH * TT * DD;
    u16* Vtb = Kb + (size_t)BHH * TT * DD;
    u16* Yb  = Vtb + (size_t)BHH * TT * DD;           // 8192*1024

    k_f2b<<<dim3(MROWS * CC / 1024), 256, 0, stream>>>(X, Xb, MROWS * CC);
    k_transpose_cvt<<<dim3(96, 32), 256, 0, stream>>>(Wa, WtA, 1024, 3072);
    k_transpose_cvt<<<dim3(32, 32), 256, 0, stream>>>(Wp, WtP, 1024, 1024);
    k_gemm_qkv<<<dim3(1536), 256, 0, stream>>>(Xb, WtA, ba, Qb, Kb, Vtb);
    k_attn<<<dim3(1024), 256, 0, stream>>>(Qb, Kb, Vtb, Yb);
    k_gemm_proj<<<dim3(512), 256, 0, stream>>>(Yb, WtP, bp, out);
}

// Round 18
// 172.570 us; speedup vs baseline: 1.0694x; 1.0288x over previous
//
#include <hip/hip_runtime.h>
#include <stdint.h>

// Problem constants
#define NB 4
#define TT 2048
#define CC 1024
#define NH 16
#define DD 64
#define BHH (NB*NH)     // 64 (b,h) pairs
#define MROWS (NB*TT)   // 8192

typedef uint16_t u16;
typedef uint32_t u32;
typedef __bf16 bf16x8 __attribute__((ext_vector_type(8)));
typedef float f32x4 __attribute__((ext_vector_type(4)));
typedef float f32x16 __attribute__((ext_vector_type(16)));

__device__ __forceinline__ u16 f2bf(float f) {
    union { float f; uint32_t u; } v; v.f = f;
    uint32_t u = v.u;
    return (u16)((u + 0x7FFF + ((u >> 16) & 1)) >> 16);   // RNE
}

__device__ __forceinline__ u32 cvtpk(float lo, float hi) {
    u32 r;
    asm volatile("v_cvt_pk_bf16_f32 %0, %1, %2" : "=v"(r) : "v"(lo), "v"(hi));
    return r;
}

__device__ __forceinline__ void plswap(u32& a, u32& b) {
    asm volatile("v_permlane32_swap_b32 %0, %1" : "+v"(a), "+v"(b));
}

__device__ __forceinline__ bf16x8 mk8(u32 a, u32 b, u32 c, u32 d) {
    union { u32 u[4]; bf16x8 v; } x;
    x.u[0] = a; x.u[1] = b; x.u[2] = c; x.u[3] = d;
    return x.v;
}

__device__ __forceinline__ void gl_lds16(const u16* g, u16* l) {
    __builtin_amdgcn_global_load_lds(
        (const __attribute__((address_space(1))) unsigned int*)g,
        (__attribute__((address_space(3))) unsigned int*)l, 16, 0, 0);
}

__device__ __forceinline__ f32x16 mfma32(bf16x8 a, bf16x8 b, f32x16 c) {
    return __builtin_amdgcn_mfma_f32_32x32x16_bf16(a, b, c, 0, 0, 0);
}

#define VM8()  do { asm volatile("s_waitcnt vmcnt(8)" ::: "memory"); \
                    __builtin_amdgcn_sched_barrier(0); } while (0)
#define VM0()  do { asm volatile("s_waitcnt vmcnt(0)" ::: "memory"); \
                    __builtin_amdgcn_sched_barrier(0); } while (0)

// ---------------------------------------------------------------------------
// k_prep: fused pre-pass (single launch, three independent block ranges)
//   blocks    0..2047: X f32 -> bf16, grid-strided (4 float4/thread-iter)
//   blocks 2048..5119: Wa [1024][3072] -> WtA [3072][1024] (transpose+cvt)
//   blocks 5120..6143: Wp [1024][1024] -> WtP [1024][1024] (transpose+cvt)
// ---------------------------------------------------------------------------
__global__ __launch_bounds__(256) void k_prep(const float* __restrict__ X,
                                              u16* __restrict__ Xb,
                                              const float* __restrict__ Wa,
                                              u16* __restrict__ WtA,
                                              const float* __restrict__ Wp,
                                              u16* __restrict__ WtP) {
    const int id = blockIdx.x;
    if (id < 2048) {
        // ---- f2b, grid-stride over 2,097,152 float4 quads ----
        const int nq = MROWS * CC / 4;
        for (int q = id * 256 + threadIdx.x; q < nq; q += 2048 * 256) {
            const int i = q * 4;
            const float4 v = *(const float4*)(X + i);
            ushort4 o;
            o.x = f2bf(v.x); o.y = f2bf(v.y); o.z = f2bf(v.z); o.w = f2bf(v.w);
            *(ushort4*)(Xb + i) = o;
        }
        return;
    }
    // ---- transpose+convert path ----
    __shared__ float tbuf[32][33];
    const float* in;
    u16* out;
    int R, N, n0, r0;
    if (id < 2048 + 3072) {
        const int t = id - 2048;
        in = Wa; out = WtA; R = 1024; N = 3072;
        n0 = (t % 96) * 32; r0 = (t / 96) * 32;
    } else {
        const int t = id - 5120;
        in = Wp; out = WtP; R = 1024; N = 1024;
        n0 = (t & 31) * 32; r0 = (t >> 5) * 32;
    }
    const int c = threadIdx.x & 31, rq = threadIdx.x >> 5;
#pragma unroll
    for (int i = 0; i < 4; ++i) {
        const int r = rq + i * 8;
        tbuf[r][c] = in[(r0 + r) * N + n0 + c];
    }
    __syncthreads();
#pragma unroll
    for (int i = 0; i < 4; ++i) {
        const int r = rq + i * 8;
        out[(n0 + r) * R + r0 + c] = f2bf(tbuf[c][r]);
    }
}

// ===========================================================================
// gemm128v5 (round-15, frozen): 128x128, BK=64, dbuf, counted vmcnt, mfma32.
// QKV is at the 2-phase structural floor (~628 TF = m233's measured band):
// r7/r12/r13/r14/r15 falsified fetch/occupancy/barrier/geometry/inst-count.
// ===========================================================================
__device__ __forceinline__ void gemm128v5(const u16* __restrict__ A,
                                          const u16* __restrict__ Bt,
                                          int m0, int n0, f32x16 acc[2][2]) {
    __shared__ __align__(16) u16 As[2][128 * 64];
    __shared__ __align__(16) u16 Bs[2][128 * 64];
    const int tid = threadIdx.x, l = tid & 63, w = tid >> 6;
    const int wr = w >> 1, wc = w & 1;
    const int lq = l & 31, hi = l >> 5;

    auto stage = [&](int kt, int b) {
#pragma unroll
        for (int line = 0; line < 4; ++line) {
            const int s = line * 4096 + tid * 16;        // linear dest byte
            const int row = s >> 7;                      // 0..127
            const int colb = (s & 127) ^ ((row & 7) << 4);
            const int ldsoff = (line * 4096 + w * 1024) >> 1;
            gl_lds16(A  + (size_t)(m0 + row) * 1024 + kt * 64 + (colb >> 1),
                     &As[b][ldsoff]);
            gl_lds16(Bt + (size_t)(n0 + row) * 1024 + kt * 64 + (colb >> 1),
                     &Bs[b][ldsoff]);
        }
    };

    stage(0, 0);
    stage(1, 1);
    VM8();
    __builtin_amdgcn_s_barrier();

    for (int kt = 0; kt < 16; ++kt) {
        const int b = kt & 1;
#pragma unroll
        for (int ksl = 0; ksl < 4; ++ksl) {
            bf16x8 af[2], bf[2];
#pragma unroll
            for (int mt = 0; mt < 2; ++mt) {
                const int row = wr * 64 + mt * 32 + lq;
                const int byteC = (ksl * 32 + hi * 16) ^ ((row & 7) << 4);
                af[mt] = *(const bf16x8*)&As[b][(row * 128 + byteC) >> 1];
            }
#pragma unroll
            for (int nt = 0; nt < 2; ++nt) {
                const int row = wc * 64 + nt * 32 + lq;
                const int byteC = (ksl * 32 + hi * 16) ^ ((row & 7) << 4);
                bf[nt] = *(const bf16x8*)&Bs[b][(row * 128 + byteC) >> 1];
            }
            acc[0][0] = mfma32(af[0], bf[0], acc[0][0]);
            acc[0][1] = mfma32(af[0], bf[1], acc[0][1]);
            acc[1][0] = mfma32(af[1], bf[0], acc[1][0]);
            acc[1][1] = mfma32(af[1], bf[1], acc[1][1]);
        }

        if (kt == 15) break;

        __builtin_amdgcn_s_barrier();
        if (kt + 2 < 16) {
            stage(kt + 2, b);
            VM8();
        } else {
            VM0();
        }
        __builtin_amdgcn_s_barrier();
    }
}

// ---------------------------------------------------------------------------
// QKV GEMM (gemm128v5) + XCD-chunked swizzle + bias, scatter Q/K/Vt
// Q pre-scaled by 0.125*log2(e) (v6-proven): attn gets log2-domain scores.
// ---------------------------------------------------------------------------
__global__ __launch_bounds__(256, 2) void k_gemm_qkv(const u16* __restrict__ X,
                                                     const u16* __restrict__ Wt,
                                                     const float* __restrict__ bias,
                                                     u16* __restrict__ Qo,
                                                     u16* __restrict__ Ko,
                                                     u16* __restrict__ Vto) {
    const int id = blockIdx.x;
    const int xcd = id & 7, lid = id >> 3;     // lid 0..191
    const int lm = lid & 7, ln = lid >> 3;     // 8 m x 24 n per XCD
    const int m0 = (xcd * 8 + lm) * 128;
    const int n0 = ln * 128;

    f32x16 acc[2][2] = {};
    gemm128v5(X, Wt, m0, n0, acc);

    const float C2 = 0.18033688011112042f;     // 0.125 * log2(e)
    const int tid = threadIdx.x, l = tid & 63, w = tid >> 6;
    const int wr = w >> 1, wc = w & 1, lq = l & 31, hi = l >> 5;
#pragma unroll
    for (int nt = 0; nt < 2; ++nt) {
        const int c = n0 + wc * 64 + nt * 32 + lq;
        const float bv = bias[c];
        const int which = c >> 10, cc = c & 1023, h = cc >> 6, d = cc & 63;
#pragma unroll
        for (int mt = 0; mt < 2; ++mt) {
#pragma unroll
            for (int r = 0; r < 16; ++r) {
                const int rowl = (r & 3) + 8 * (r >> 2) + 4 * hi;
                const int row = m0 + wr * 64 + mt * 32 + rowl;
                const int b = row >> 11, t = row & 2047;
                const int bh = b * NH + h;
                const float v = acc[mt][nt][r] + bv;
                if (which == 0)      Qo[(bh * TT + t) * DD + d] = f2bf(v * C2);
                else if (which == 1) Ko[(bh * TT + t) * DD + d] = f2bf(v);
                else                 Vto[(bh * DD + d) * TT + t] = f2bf(v);
            }
        }
    }
}

// ---------------------------------------------------------------------------
// Proj GEMM (gemm128v5) + XCD swizzle + bias -> out f32 [8192][1024]
// ---------------------------------------------------------------------------
__global__ __launch_bounds__(256, 2) void k_gemm_proj(const u16* __restrict__ Yin,
                                                      const u16* __restrict__ Wt,
                                                      const float* __restrict__ bias,
                                                      float* __restrict__ out) {
    const int id = blockIdx.x;
    const int xcd = id & 7, lid = id >> 3;     // lid 0..63
    const int lm = lid & 7, ln = lid >> 3;     // 8 m x 8 n per XCD
    const int m0 = (xcd * 8 + lm) * 128;
    const int n0 = ln * 128;

    f32x16 acc[2][2] = {};
    gemm128v5(Yin, Wt, m0, n0, acc);

    const int tid = threadIdx.x, l = tid & 63, w = tid >> 6;
    const int wr = w >> 1, wc = w & 1, lq = l & 31, hi = l >> 5;
#pragma unroll
    for (int nt = 0; nt < 2; ++nt) {
        const int c = n0 + wc * 64 + nt * 32 + lq;
        const float bv = bias[c];
#pragma unroll
        for (int mt = 0; mt < 2; ++mt) {
#pragma unroll
            for (int r = 0; r < 16; ++r) {
                const int rowl = (r & 3) + 8 * (r >> 2) + 4 * hi;
                const int row = m0 + wr * 64 + mt * 32 + rowl;
                out[row * CC + c] = acc[mt][nt][r] + bv;
            }
        }
    }
}

// ---------------------------------------------------------------------------
// Causal flash attention v7 (round-15 exact: KVBLK=64, log2-domain scores,
// T13 threshold rescale; no setprio — r17 showed null)
// ---------------------------------------------------------------------------
__global__ __launch_bounds__(256) void k_attn(const u16* __restrict__ Qg_,
                                              const u16* __restrict__ Kg_,
                                              const u16* __restrict__ Vg_,
                                              u16* __restrict__ Y) {
    __shared__ __align__(16) u16 Ks[2][64 * 64];
    __shared__ __align__(16) u16 Vs[2][64 * 64];

    const int id = blockIdx.x;
    const int qi = 15 - (id >> 6);         // work-descending
    const int bh = id & 63;
    const int q0 = qi * 128;
    const u16* Qg = Qg_ + (size_t)bh * TT * DD;
    const u16* Kg = Kg_ + (size_t)bh * TT * DD;
    const u16* Vg = Vg_ + (size_t)bh * DD * TT;
    const int tid = threadIdx.x, l = tid & 63, w = tid >> 6;
    const int lq = l & 31, hi = l >> 5;
    const int qs = q0 + w * 32;

    unsigned dmask = 0;
#pragma unroll
    for (int r = 0; r < 16; ++r) {
        const int kvloc = (r & 3) + 8 * (r >> 2) + 4 * hi;
        if (kvloc > lq) dmask |= (1u << r);
    }

    const u16* qrow = Qg + (qs + lq) * DD + hi * 8;
    bf16x8 qf0 = *(const bf16x8*)(qrow);
    bf16x8 qf1 = *(const bf16x8*)(qrow + 16);
    bf16x8 qf2 = *(const bf16x8*)(qrow + 32);
    bf16x8 qf3 = *(const bf16x8*)(qrow + 48);

    f32x16 o0 = {}, o1 = {};
    float mrun = -1e30f, lrun = 0.f;
    const int nt = 2 * qi + 2;

    auto stage = [&](int t, int b) {
        const int kv0 = t * 64;
#pragma unroll
        for (int iss = 0; iss < 2; ++iss) {
            const int s = iss * 4096 + tid * 16;
            const int row = s >> 7;
            const int colb = (s & 127) ^ ((row & 7) << 4);
            const int ldsoff = (iss * 4096 + w * 1024) >> 1;
            gl_lds16(Kg + (kv0 + row) * DD + (colb >> 1), &Ks[b][ldsoff]);
            gl_lds16(Vg + row * TT + kv0 + (colb >> 1),   &Vs[b][ldsoff]);
        }
    };

    stage(0, 0);
    __syncthreads();

    for (int t = 0; t < nt; ++t) {
        const int b = t & 1;
        if (t + 1 < nt) stage(t + 1, b ^ 1);
        const int kv0 = t * 64;

#pragma unroll
        for (int s = 0; s < 2; ++s) {
            const int kvs = kv0 + 32 * s;
            if (kvs > qs) continue;

            // ---- S^T (log2 domain) = K Q' from LDS ----
            f32x16 st = {};
#pragma unroll
            for (int i = 0; i < 4; ++i) {
                const int row = 32 * s + lq;
                const int byte = (32 * i + 16 * hi) ^ ((row & 7) << 4);
                const bf16x8 kf = *(const bf16x8*)&Ks[b][(row * 128 + byte) >> 1];
                if (i == 0) st = mfma32(kf, qf0, st);
                else if (i == 1) st = mfma32(kf, qf1, st);
                else if (i == 2) st = mfma32(kf, qf2, st);
                else st = mfma32(kf, qf3, st);
            }

            if (kvs == qs) {                   // diagonal: causal mask
#pragma unroll
                for (int r = 0; r < 16; ++r)
                    if ((dmask >> r) & 1) st[r] = -1e30f;
            }

            // ---- column max (in-lane + partner exchange) ----
            float mx = st[0];
#pragma unroll
            for (int r = 1; r < 16; ++r) mx = fmaxf(mx, st[r]);
            mx = fmaxf(mx, __shfl_xor(mx, 32));

            // T13: rescale only when growth exceeds 8 (P then <= 2^8)
            if (!__all(mx - mrun <= 8.0f)) {
                const float mn = fmaxf(mrun, mx);
                const float scl = __builtin_amdgcn_exp2f(mrun - mn);
                mrun = mn;
                lrun *= scl;
#pragma unroll
                for (int r = 0; r < 16; ++r) { o0[r] *= scl; o1[r] *= scl; }
            }

            // ---- P = exp2(st - m); psum; pack to bf16 pairs ----
            float psum = 0.f;
            u32 pk0, pk1, pk2, pk3, pk4, pk5, pk6, pk7;
            {
                float pa, pb;
                pa = __builtin_amdgcn_exp2f(st[0] - mrun);
                pb = __builtin_amdgcn_exp2f(st[1] - mrun);
                psum += pa + pb; pk0 = cvtpk(pa, pb);
                pa = __builtin_amdgcn_exp2f(st[2] - mrun);
                pb = __builtin_amdgcn_exp2f(st[3] - mrun);
                psum += pa + pb; pk1 = cvtpk(pa, pb);
                pa = __builtin_amdgcn_exp2f(st[4] - mrun);
                pb = __builtin_amdgcn_exp2f(st[5] - mrun);
                psum += pa + pb; pk2 = cvtpk(pa, pb);
                pa = __builtin_amdgcn_exp2f(st[6] - mrun);
                pb = __builtin_amdgcn_exp2f(st[7] - mrun);
                psum += pa + pb; pk3 = cvtpk(pa, pb);
                pa = __builtin_amdgcn_exp2f(st[8] - mrun);
                pb = __builtin_amdgcn_exp2f(st[9] - mrun);
                psum += pa + pb; pk4 = cvtpk(pa, pb);
                pa = __builtin_amdgcn_exp2f(st[10] - mrun);
                pb = __builtin_amdgcn_exp2f(st[11] - mrun);
                psum += pa + pb; pk5 = cvtpk(pa, pb);
                pa = __builtin_amdgcn_exp2f(st[12] - mrun);
                pb = __builtin_amdgcn_exp2f(st[13] - mrun);
                psum += pa + pb; pk6 = cvtpk(pa, pb);
                pa = __builtin_amdgcn_exp2f(st[14] - mrun);
                pb = __builtin_amdgcn_exp2f(st[15] - mrun);
                psum += pa + pb; pk7 = cvtpk(pa, pb);
            }
            lrun += psum;

            plswap(pk0, pk2); plswap(pk1, pk3);
            plswap(pk4, pk6); plswap(pk5, pk7);
            const bf16x8 pf0 = mk8(pk0, pk1, pk2, pk3);   // kv +0..15
            const bf16x8 pf1 = mk8(pk4, pk5, pk6, pk7);   // kv +16..31

            // ---- O^T += V^T P from LDS (A = V^T: row=d, k=kv) ----
#pragma unroll
            for (int dh = 0; dh < 2; ++dh) {
#pragma unroll
                for (int ks = 0; ks < 2; ++ks) {
                    const int row = 32 * dh + lq;
                    const int byte = (64 * s + 32 * ks + 16 * hi) ^ ((row & 7) << 4);
                    const bf16x8 vf = *(const bf16x8*)&Vs[b][(row * 128 + byte) >> 1];
                    if (dh == 0) o0 = mfma32(vf, ks ? pf1 : pf0, o0);
                    else         o1 = mfma32(vf, ks ? pf1 : pf0, o1);
                }
            }
        }
        if (t + 1 < nt) __syncthreads();
    }

    lrun += __shfl_xor(lrun, 32);
    const float inv = 1.0f / lrun;
    const int bb = bh >> 4, h = bh & 15;
    u16* yrow = Y + (size_t)(bb * TT + qs + lq) * CC + h * DD;
#pragma unroll
    for (int rq = 0; rq < 4; ++rq) {
        const int d0 = 8 * rq + 4 * hi;
        const u32 w0 = cvtpk(o0[rq * 4 + 0] * inv, o0[rq * 4 + 1] * inv);
        const u32 w1 = cvtpk(o0[rq * 4 + 2] * inv, o0[rq * 4 + 3] * inv);
        *(uint2*)&yrow[d0] = make_uint2(w0, w1);
        const u32 w2 = cvtpk(o1[rq * 4 + 0] * inv, o1[rq * 4 + 1] * inv);
        const u32 w3 = cvtpk(o1[rq * 4 + 2] * inv, o1[rq * 4 + 3] * inv);
        *(uint2*)&yrow[32 + d0] = make_uint2(w2, w3);
    }
}

// ---------------------------------------------------------------------------
extern "C" void kernel_launch(void* const* d_in, const int* in_sizes, int n_in,
                              void* d_out, int out_size, void* d_ws, size_t ws_size,
                              hipStream_t stream) {
    const float* X  = (const float*)d_in[0];   // [4,2048,1024] f32
    const float* Wa = (const float*)d_in[1];   // [1024,3072]  f32
    const float* ba = (const float*)d_in[2];   // [3072]       f32
    const float* Wp = (const float*)d_in[3];   // [1024,1024]  f32
    const float* bp = (const float*)d_in[4];   // [1024]       f32
    float* out = (float*)d_out;                // [8192,1024]  f32

    u16* ws  = (u16*)d_ws;
    u16* Xb  = ws;                                    // 8192*1024
    u16* WtA = Xb + (size_t)MROWS * CC;               // 3072*1024
    u16* WtP = WtA + 3072 * 1024;                     // 1024*1024
    u16* Qb  = WtP + 1024 * 1024;                     // 64*2048*64
    u16* Kb  = Qb + (size_t)BHH * TT * DD;
    u16* Vtb = Kb + (size_t)BHH * TT * DD;
    u16* Yb  = Vtb + (size_t)BHH * TT * DD;           // 8192*1024

    k_prep<<<dim3(6144), 256, 0, stream>>>(X, Xb, Wa, WtA, Wp, WtP);
    k_gemm_qkv<<<dim3(1536), 256, 0, stream>>>(Xb, WtA, ba, Qb, Kb, Vtb);
    k_attn<<<dim3(1024), 256, 0, stream>>>(Qb, Kb, Vtb, Yb);
    k_gemm_proj<<<dim3(512), 256, 0, stream>>>(Yb, WtP, bp, out);
}